// Round 16
// baseline (341.159 us; speedup 1.0000x reference)
//
#include <hip/hip_runtime.h>
#include <hip/hip_fp16.h>

// Sizes fixed by the reference.
#define BB 2
#define HH 16
#define SS 2048
#define DD 128
#define CH 64              // keys per staged K/V chunk (16 KB f16 each)
#define NCH 32             // SS / CH
#define QBLK 32            // q-rows per block
#define CSHIFT 14.0f       // E' = exp(s-14); s max ~16 -> E' f16-safe; shift cancels in softmax
#define MNEG  -10000.0f    // masked C-init: exp(s-10000) underflows to exact 0.0f

typedef __attribute__((ext_vector_type(8))) _Float16 f16x8;
typedef __attribute__((ext_vector_type(4))) _Float16 f16x4;
typedef __attribute__((ext_vector_type(4))) float    f32x4;

__device__ __forceinline__ void load_lds16(const void* g, void* l) {
  __builtin_amdgcn_global_load_lds(
      (const __attribute__((address_space(1))) void*)g,
      (__attribute__((address_space(3))) void*)l, 16, 0, 0);
}

__device__ __forceinline__ void block_barrier() {
  asm volatile("" ::: "memory");
  __builtin_amdgcn_s_barrier();
  asm volatile("" ::: "memory");
}

// k_norm = k / max(||k||_2 over HEAD axis, eps), f16, PRE-SWIZZLED row layout:
// (s,d) at s*128 + (((d>>3)^(s&7))<<3) + (d&7). Linear global_load_lds then
// gives conflict-free XOR-swizzled fragment reads in LDS.
__global__ void knorm_f16(const float* __restrict__ k, _Float16* __restrict__ kh) {
  int t = blockIdx.x * 256 + threadIdx.x;      // [0, B*S*D)
  int d = t & (DD - 1);
  int s = (t >> 7) & (SS - 1);
  int b = t >> 18;                              // S*D = 2^18
  const float* kp = k + (size_t)b * HH * SS * DD + (size_t)s * DD + d;
  float vals[HH];
  float ss = 0.f;
  #pragma unroll
  for (int h = 0; h < HH; ++h) { float x = kp[(size_t)h * SS * DD]; vals[h] = x; ss += x * x; }
  float r = 1.0f / fmaxf(sqrtf(ss), 1e-12f);
  const int doff = (((d >> 3) ^ (s & 7)) << 3) + (d & 7);
  _Float16* op = kh + (size_t)b * HH * SS * DD + (size_t)s * DD + doff;
  #pragma unroll
  for (int h = 0; h < HH; ++h) op[(size_t)h * SS * DD] = (_Float16)(vals[h] * r);
}

// q -> f16, 8 elements/thread (plain layout).
__global__ void cvt_f16(const float* __restrict__ x, _Float16* __restrict__ y) {
  size_t i = ((size_t)blockIdx.x * 256 + threadIdx.x) * 8;
  float4 a = *(const float4*)(x + i);
  float4 b = *(const float4*)(x + i + 4);
  f16x8 r = { (_Float16)a.x, (_Float16)a.y, (_Float16)a.z, (_Float16)a.w,
              (_Float16)b.x, (_Float16)b.y, (_Float16)b.z, (_Float16)b.w };
  *(f16x8*)(y + i) = r;
}

// v[b,h,s,d] -> V^T in 64-key chunk-major swizzled layout: chunk c = key>>6 is
// a 16 KB block [d][64 keys]; element (d,key) at
// c*8192 + d*64 + ((((key&63)>>3) ^ (d&7))<<3) + (key&7).
__global__ void vtrans_f16(const float* __restrict__ v, _Float16* __restrict__ vt) {
  __shared__ float tile[32][33];
  int bh = blockIdx.z;
  int d0 = blockIdx.x * 32, s0 = blockIdx.y * 32;
  const float* vp = v + (size_t)bh * SS * DD;
  _Float16* tp = vt + (size_t)bh * SS * DD;
  int tx = threadIdx.x, ty = threadIdx.y;       // block (32,8)
  #pragma unroll
  for (int i = ty; i < 32; i += 8)
    tile[i][tx] = vp[(size_t)(s0 + i) * DD + d0 + tx];
  __syncthreads();
  #pragma unroll
  for (int i = ty; i < 32; i += 8) {
    const int key = s0 + tx, dd = d0 + i;
    tp[(size_t)(key >> 6) * (DD * CH) + (size_t)dd * CH
       + ((((key & 63) >> 3) ^ (dd & 7)) << 3) + (key & 7)] = (_Float16)tile[tx][i];
  }
}

// ---------------- Fused attention (r16): r15 + critical-path surgery --------
// 512 thr (8 waves), QBLK=32, CH=64, 2 blocks/CU, 1 barrier/chunk (r15).
// New: (1) mask int4 prefetched one chunk ahead into regs (L1 latency off the
// chain); (2) mask folded into the MFMA C-INIT (a starts at -14 or -1e4;
// exp() applies directly -> no post-MFMA selects, masked lanes underflow to
// exact 0); (3) s_setprio(1) around both MFMA clusters (T5).
__global__ __launch_bounds__(512, 4) void attn_fused(
    const _Float16* __restrict__ qh, const _Float16* __restrict__ kh,
    const _Float16* __restrict__ vth, const int* __restrict__ mask,
    float* __restrict__ out, float* __restrict__ attn)
{
  __shared__ _Float16 kbuf[2][CH * DD];      // 32 KB
  __shared__ _Float16 vbuf[2][DD * CH];      // 32 KB
  __shared__ _Float16 pbuf[2][QBLK * CH];    // 8 KB
  __shared__ float redsum[2][16][5];         // [q-half][q][sub], padded

  // XCD swizzle: wgid%8 = XCD; each XCD owns 4 heads, walks their q-tiles.
  const int wgid = blockIdx.x;                  // [0, 2048)
  const int xcd  = wgid & 7;
  const int idx  = wgid >> 3;                   // [0, 256)
  const int bh   = (xcd << 2) | (idx >> 6);     // 4 heads per XCD
  const int q0   = (idx & 63) * QBLK;
  const int b    = bh >> 4;

  const int tid  = threadIdx.x;
  const int lane = tid & 63;
  const int w    = tid >> 6;                    // [0,8)
  const int lo16 = lane & 15;
  const int g    = lane >> 4;
  const int qhf  = w >> 2;                      // q-half
  const int sub  = w & 3;                       // key/d subtile

  const size_t hoff = (size_t)bh * SS * DD;
  const _Float16* Q = qh  + hoff + (size_t)q0 * DD;
  const _Float16* K = kh  + hoff;               // pre-swizzled [2048][128]
  const _Float16* V = vth + hoff;               // 64-key chunk-major swizzled
  const int* mrow = mask + b * SS + sub * 16 + g * 4;

  const int prow = qhf * 16 + lo16;             // this lane's q row

  f16x8 qf[4];
  #pragma unroll
  for (int c = 0; c < 4; ++c)
    qf[c] = *(const f16x8*)(Q + (size_t)prow * DD + c * 32 + g * 8);

  // ---- Prologue: stage K chunk 0; prefetch mask chunk 0 ----
  #pragma unroll
  for (int j = 0; j < 2; ++j) {
    const int slot = tid + j * 512;
    load_lds16(K + slot * 8, &kbuf[0][slot * 8]);
  }
  int4 mv = *(const int4*)(mrow);               // mask for chunk 0
  __syncthreads();

  f16x4 acc_h[NCH];                             // E' (4 keys/lane/chunk), 64 VGPRs
  f32x4 oacc[2] = { {0,0,0,0}, {0,0,0,0} };
  float ssum = 0.f;

  #pragma unroll
  for (int c = 0; c < NCH; ++c) {
    const _Float16* kb = kbuf[c & 1];

    // ---- issue staging: K(c+1) and V(c); prefetch mask(c+1) ----
    if (c + 1 < NCH) {
      #pragma unroll
      for (int j = 0; j < 2; ++j) {
        const int slot = tid + j * 512;
        load_lds16(K + (size_t)(c + 1) * (CH * DD) + slot * 8,
                   &kbuf[(c + 1) & 1][slot * 8]);
      }
    }
    #pragma unroll
    for (int j = 0; j < 2; ++j) {
      const int slot = tid + j * 512;
      load_lds16(V + (size_t)c * (CH * DD) + slot * 8,
                 &vbuf[c & 1][slot * 8]);
    }
    int4 mvn = mv;
    if (c + 1 < NCH) mvn = *(const int4*)(mrow + (c + 1) * CH);

    // ---- QK^T(c): keys [sub*16,+16) x q-half qhf; mask folded into C-init --
    {
      const int row = sub * 16 + lo16;          // key row within chunk [0,64)
      f32x4 a = { mv.x ? -CSHIFT : MNEG, mv.y ? -CSHIFT : MNEG,
                  mv.z ? -CSHIFT : MNEG, mv.w ? -CSHIFT : MNEG };
      __builtin_amdgcn_s_setprio(1);
      #pragma unroll
      for (int cc = 0; cc < 4; ++cc) {
        const int p = (cc * 4 + g) ^ (row & 7); // swizzled 16B slot
        f16x8 kf = *(const f16x8*)(kb + row * DD + p * 8);
        a = __builtin_amdgcn_mfma_f32_16x16x32_f16(kf, qf[cc], a, 0, 0, 0);
      }
      __builtin_amdgcn_s_setprio(0);
      // D[key][q]: lane holds q=prow, keys sub*16 + g*4 + i (pre-shifted)
      const float e0 = __expf(a[0]);
      const float e1 = __expf(a[1]);
      const float e2 = __expf(a[2]);
      const float e3 = __expf(a[3]);
      ssum += (e0 + e1) + (e2 + e3);
      f16x4 eh = { (_Float16)e0, (_Float16)e1, (_Float16)e2, (_Float16)e3 };
      acc_h[c] = eh;
      const int col = sub * 16 + g * 4;         // key col in pbuf row [0,64)
      *(f16x4*)(&pbuf[c & 1][prow * CH + (((col >> 3) ^ (prow & 7)) << 3) + (col & 7)]) = eh;
    }
    mv = mvn;

    // ---- PV(c-1): d-cols [sub*32,+32) x q-half qhf, from vbuf[(c-1)&1] ----
    if (c > 0) {
      const _Float16* vb = vbuf[(c - 1) & 1];
      const _Float16* pb = pbuf[(c - 1) & 1];
      __builtin_amdgcn_s_setprio(1);
      #pragma unroll
      for (int t = 0; t < 2; ++t) {
        const int dcol = sub * 32 + t * 16 + lo16;
        #pragma unroll
        for (int ks = 0; ks < 2; ++ks) {
          const int pv_ = (ks * 4 + g) ^ (dcol & 7);
          f16x8 vf = *(const f16x8*)(vb + dcol * CH + pv_ * 8);
          f16x8 pf = *(const f16x8*)(pb + prow * CH + ((ks * 32 + g * 8) ^ ((prow & 7) << 3)));
          oacc[t] = __builtin_amdgcn_mfma_f32_16x16x32_f16(pf, vf, oacc[t], 0, 0, 0);
        }
      }
      __builtin_amdgcn_s_setprio(0);
    }

    asm volatile("s_waitcnt lgkmcnt(0)" ::: "memory");  // pbuf(c) visible
    asm volatile("s_waitcnt vmcnt(0)"  ::: "memory");   // K(c+1), V(c) resident
    block_barrier();                                    // ONE barrier per chunk
  }

  // ---- Tail: PV(NCH-1) (vbuf/pbuf written before the last barrier) ----
  {
    const _Float16* vb = vbuf[(NCH - 1) & 1];
    const _Float16* pb = pbuf[(NCH - 1) & 1];
    #pragma unroll
    for (int t = 0; t < 2; ++t) {
      const int dcol = sub * 32 + t * 16 + lo16;
      #pragma unroll
      for (int ks = 0; ks < 2; ++ks) {
        const int pv_ = (ks * 4 + g) ^ (dcol & 7);
        f16x8 vf = *(const f16x8*)(vb + dcol * CH + pv_ * 8);
        f16x8 pf = *(const f16x8*)(pb + prow * CH + ((ks * 32 + g * 8) ^ ((prow & 7) << 3)));
        oacc[t] = __builtin_amdgcn_mfma_f32_16x16x32_f16(pf, vf, oacc[t], 0, 0, 0);
      }
    }
  }

  // ---- Epilogue: denominators, attn from regs, out from oacc ----
  ssum += __shfl_xor(ssum, 16);                 // reduce over g groups
  ssum += __shfl_xor(ssum, 32);
  if (lane < 16) redsum[qhf][lane][sub] = ssum;
  __syncthreads();

  float denom = 0.f;
  #pragma unroll
  for (int j = 0; j < 4; ++j) denom += redsum[qhf][lo16][j];
  const float inv = 1.0f / denom;

  // attn[q0+prow][c*64 + sub*16 + g*4 ..+3] = E' * inv (f32, from registers)
  float* arow = attn + ((size_t)bh * SS + q0 + prow) * SS + sub * 16 + g * 4;
  #pragma unroll
  for (int c = 0; c < NCH; ++c) {
    f32x4 pst = { (float)acc_h[c][0] * inv, (float)acc_h[c][1] * inv,
                  (float)acc_h[c][2] * inv, (float)acc_h[c][3] * inv };
    *(f32x4*)(arow + c * CH) = pst;
  }

  // out: C row = q = qhf*16 + g*4 + i, col = d = sub*32 + t*16 + lo16
  float* O = out + hoff + (size_t)q0 * DD + sub * 32;
  #pragma unroll
  for (int i = 0; i < 4; ++i) {
    const int qr = g * 4 + i;
    float dq = 0.f;
    #pragma unroll
    for (int j = 0; j < 4; ++j) dq += redsum[qhf][qr][j];
    const float rdq = 1.0f / dq;
    #pragma unroll
    for (int t = 0; t < 2; ++t)
      O[(size_t)(qhf * 16 + qr) * DD + t * 16 + lo16] = oacc[t][i] * rdq;
  }
}

extern "C" void kernel_launch(void* const* d_in, const int* in_sizes, int n_in,
                              void* d_out, int out_size, void* d_ws, size_t ws_size,
                              hipStream_t stream) {
  const float* q    = (const float*)d_in[0];
  const float* k    = (const float*)d_in[1];
  const float* v    = (const float*)d_in[2];
  const int*   mask = (const int*)d_in[3];

  const size_t N = (size_t)BB * HH * SS * DD;     // 8388608
  float* out  = (float*)d_out;
  float* attn = out + N;                          // outputs concatenated (out, attn)

  // scratch: 3 f16 tensors = 48 MB
  _Float16* qh  = (_Float16*)d_ws;
  _Float16* kh  = qh + N;
  _Float16* vth = kh + N;

  cvt_f16  <<<N / 8 / 256, 256, 0, stream>>>(q, qh);
  knorm_f16<<<(BB * SS * DD) / 256, 256, 0, stream>>>(k, kh);
  vtrans_f16<<<dim3(DD / 32, SS / 32, BB * HH), dim3(32, 8), 0, stream>>>(v, vth);

  // 64 q-tiles x 32 heads, XCD-swizzled inside the kernel
  attn_fused<<<2048, 512, 0, stream>>>(qh, kh, vth, mask, out, attn);
}

// Round 17
// 316.378 us; speedup vs baseline: 1.0783x; 1.0783x over previous
//
#include <hip/hip_runtime.h>
#include <hip/hip_fp16.h>

// Sizes fixed by the reference.
#define BB 2
#define HH 16
#define SS 2048
#define DD 128
#define CH 64              // keys per staged chunk (16 KB f16)
#define NCH 32             // SS / CH
#define QBLK 64            // q-rows per block
#define CSHIFT 14.0f       // E' = exp(s-14); s max ~16 -> E' f16-safe; shift cancels in softmax

typedef __attribute__((ext_vector_type(8))) _Float16 f16x8;
typedef __attribute__((ext_vector_type(4))) _Float16 f16x4;
typedef __attribute__((ext_vector_type(4))) float    f32x4;

__device__ __forceinline__ void load_lds16(const void* g, void* l) {
  __builtin_amdgcn_global_load_lds(
      (const __attribute__((address_space(1))) void*)g,
      (__attribute__((address_space(3))) void*)l, 16, 0, 0);
}

__device__ __forceinline__ void block_barrier() {
  asm volatile("" ::: "memory");
  __builtin_amdgcn_s_barrier();
  asm volatile("" ::: "memory");
}

// k_norm = k / max(||k||_2 over HEAD axis, eps), f16, PRE-SWIZZLED row layout:
// (s,d) at s*128 + (((d>>3)^(s&7))<<3) + (d&7). Linear global_load_lds then
// gives conflict-free XOR-swizzled fragment reads in LDS.
__global__ void knorm_f16(const float* __restrict__ k, _Float16* __restrict__ kh) {
  int t = blockIdx.x * 256 + threadIdx.x;      // [0, B*S*D)
  int d = t & (DD - 1);
  int s = (t >> 7) & (SS - 1);
  int b = t >> 18;                              // S*D = 2^18
  const float* kp = k + (size_t)b * HH * SS * DD + (size_t)s * DD + d;
  float vals[HH];
  float ss = 0.f;
  #pragma unroll
  for (int h = 0; h < HH; ++h) { float x = kp[(size_t)h * SS * DD]; vals[h] = x; ss += x * x; }
  float r = 1.0f / fmaxf(sqrtf(ss), 1e-12f);
  const int doff = (((d >> 3) ^ (s & 7)) << 3) + (d & 7);
  _Float16* op = kh + (size_t)b * HH * SS * DD + (size_t)s * DD + doff;
  #pragma unroll
  for (int h = 0; h < HH; ++h) op[(size_t)h * SS * DD] = (_Float16)(vals[h] * r);
}

// q -> f16, 8 elements/thread (plain layout).
__global__ void cvt_f16(const float* __restrict__ x, _Float16* __restrict__ y) {
  size_t i = ((size_t)blockIdx.x * 256 + threadIdx.x) * 8;
  float4 a = *(const float4*)(x + i);
  float4 b = *(const float4*)(x + i + 4);
  f16x8 r = { (_Float16)a.x, (_Float16)a.y, (_Float16)a.z, (_Float16)a.w,
              (_Float16)b.x, (_Float16)b.y, (_Float16)b.z, (_Float16)b.w };
  *(f16x8*)(y + i) = r;
}

// v[b,h,s,d] -> V^T in 64-key chunk-major swizzled layout: chunk c = key>>6 is
// a 16 KB block [d][64 keys]; element (d,key) at
// c*8192 + d*64 + ((((key&63)>>3) ^ (d&7))<<3) + (key&7).
__global__ void vtrans_f16(const float* __restrict__ v, _Float16* __restrict__ vt) {
  __shared__ float tile[32][33];
  int bh = blockIdx.z;
  int d0 = blockIdx.x * 32, s0 = blockIdx.y * 32;
  const float* vp = v + (size_t)bh * SS * DD;
  _Float16* tp = vt + (size_t)bh * SS * DD;
  int tx = threadIdx.x, ty = threadIdx.y;       // block (32,8)
  #pragma unroll
  for (int i = ty; i < 32; i += 8)
    tile[i][tx] = vp[(size_t)(s0 + i) * DD + d0 + tx];
  __syncthreads();
  #pragma unroll
  for (int i = ty; i < 32; i += 8) {
    const int key = s0 + tx, dd = d0 + i;
    tp[(size_t)(key >> 6) * (DD * CH) + (size_t)dd * CH
       + ((((key & 63) >> 3) ^ (dd & 7)) << 3) + (key & 7)] = (_Float16)tile[tx][i];
  }
}

// ---------------- Fused attention (r17): counted-vmcnt pipeline, QBLK=64 ----
// 1024 thr (16 waves), QBLK=64, CH=64. Wave w = (qq = w>>2) q-quarter x
// (sub = w&3). Triple-buffered K (staged 2 AHEAD) and V (1 ahead, issued
// first); each phase ends with s_waitcnt vmcnt(1) — K(c+2)'s load stays in
// flight ACROSS the barrier (T3/T4; r15's vmcnt(0) serialized staging into
// every phase). Buffer parities: K w(c+2)%3 / r(c)%3; V w(c+1)%3 / r(c-1)%3;
// pbuf w(c&1) / r((c-1)&1) — all disjoint.
// QBLK=64: staging traffic halves (1 GB), 4 serial blocks/CU (r15: 8).
// Regs: acc_h 64 + qf 16 + oacc 8 + temps ~ 110 < 128 (4 waves/EU): no spill.
// LDS 113 KB -> one 1024-thr block/CU (16 waves resident, same as r15's 2x8).
__global__ __launch_bounds__(1024, 4) void attn_fused(
    const _Float16* __restrict__ qh, const _Float16* __restrict__ kh,
    const _Float16* __restrict__ vth, const int* __restrict__ mask,
    float* __restrict__ out, float* __restrict__ attn)
{
  __shared__ _Float16 kbuf[3][CH * DD];      // 48 KB
  __shared__ _Float16 vbuf[3][DD * CH];      // 48 KB
  __shared__ _Float16 pbuf[2][QBLK * CH];    // 16 KB
  __shared__ float redsum[4][16][5];         // [q-quarter][q][sub], padded

  // XCD swizzle: wgid%8 = XCD; each XCD owns 4 heads, walks their q-tiles.
  const int wgid = blockIdx.x;                  // [0, 1024)
  const int xcd  = wgid & 7;
  const int idx  = wgid >> 3;                   // [0, 128)
  const int bh   = (xcd << 2) | (idx >> 5);     // 4 heads per XCD
  const int q0   = (idx & 31) * QBLK;
  const int b    = bh >> 4;

  const int tid  = threadIdx.x;
  const int lane = tid & 63;
  const int w    = tid >> 6;                    // [0,16)
  const int lo16 = lane & 15;
  const int g    = lane >> 4;
  const int qq   = w >> 2;                      // q-quarter
  const int sub  = w & 3;                       // key/d subtile

  const size_t hoff = (size_t)bh * SS * DD;
  const _Float16* Q = qh  + hoff + (size_t)q0 * DD;
  const _Float16* K = kh  + hoff;               // pre-swizzled [2048][128]
  const _Float16* V = vth + hoff;               // 64-key chunk-major swizzled
  const int* mrow = mask + b * SS;

  const int prow = qq * 16 + lo16;              // this lane's q row [0,64)

  f16x8 qf[4];
  #pragma unroll
  for (int c = 0; c < 4; ++c)
    qf[c] = *(const f16x8*)(Q + (size_t)prow * DD + c * 32 + g * 8);

  // ---- Prologue: stage V(0), K(0), K(1) (1024 thr x 16 B each) ----
  load_lds16(V + tid * 8, &vbuf[0][tid * 8]);
  load_lds16(K + tid * 8, &kbuf[0][tid * 8]);
  load_lds16(K + (size_t)(CH * DD) + tid * 8, &kbuf[1][tid * 8]);
  __syncthreads();                              // full drain once, at entry

  f16x4 acc_h[NCH];                             // E' (4 keys/lane/chunk), 64 VGPRs
  f32x4 oacc[2] = { {0,0,0,0}, {0,0,0,0} };
  float ssum = 0.f;

  #pragma unroll
  for (int c = 0; c < NCH; ++c) {
    const _Float16* kb = kbuf[c % 3];

    // ---- issue staging: V(c+1) FIRST, then K(c+2) (vmcnt order matters) ----
    if (c + 1 < NCH)
      load_lds16(V + (size_t)(c + 1) * (CH * DD) + tid * 8,
                 &vbuf[(c + 1) % 3][tid * 8]);
    if (c + 2 < NCH)
      load_lds16(K + (size_t)(c + 2) * (CH * DD) + tid * 8,
                 &kbuf[(c + 2) % 3][tid * 8]);

    // ---- QK^T(c): keys [sub*16,+16) x q-quarter qq ----
    {
      const int row = sub * 16 + lo16;          // key row within chunk [0,64)
      f32x4 a = {0.f, 0.f, 0.f, 0.f};
      #pragma unroll
      for (int cc = 0; cc < 4; ++cc) {
        const int p = (cc * 4 + g) ^ (row & 7); // swizzled 16B slot
        f16x8 kf = *(const f16x8*)(kb + row * DD + p * 8);
        a = __builtin_amdgcn_mfma_f32_16x16x32_f16(kf, qf[cc], a, 0, 0, 0);
      }
      // D[key][q]: lane holds q=prow, keys sub*16 + g*4 + i
      const int4 mv = *(const int4*)(mrow + c * CH + sub * 16 + g * 4);
      const float e0 = mv.x ? __expf(a[0] - CSHIFT) : 0.f;
      const float e1 = mv.y ? __expf(a[1] - CSHIFT) : 0.f;
      const float e2 = mv.z ? __expf(a[2] - CSHIFT) : 0.f;
      const float e3 = mv.w ? __expf(a[3] - CSHIFT) : 0.f;
      ssum += e0 + e1 + e2 + e3;
      f16x4 eh = { (_Float16)e0, (_Float16)e1, (_Float16)e2, (_Float16)e3 };
      acc_h[c] = eh;
      const int col = sub * 16 + g * 4;         // key col in pbuf row [0,64)
      *(f16x4*)(&pbuf[c & 1][prow * CH + (((col >> 3) ^ (prow & 7)) << 3) + (col & 7)]) = eh;
    }

    // ---- PV(c-1): d-cols [sub*32,+32) x q-quarter qq ----
    if (c > 0) {
      const _Float16* vb = vbuf[(c - 1) % 3];
      const _Float16* pb = pbuf[(c - 1) & 1];
      #pragma unroll
      for (int t = 0; t < 2; ++t) {
        const int dcol = sub * 32 + t * 16 + lo16;
        #pragma unroll
        for (int ks = 0; ks < 2; ++ks) {
          const int pv_ = (ks * 4 + g) ^ (dcol & 7);
          f16x8 vf = *(const f16x8*)(vb + dcol * CH + pv_ * 8);
          f16x8 pf = *(const f16x8*)(pb + prow * CH + ((ks * 32 + g * 8) ^ ((prow & 7) << 3)));
          oacc[t] = __builtin_amdgcn_mfma_f32_16x16x32_f16(pf, vf, oacc[t], 0, 0, 0);
        }
      }
    }

    asm volatile("s_waitcnt lgkmcnt(0)" ::: "memory");  // pbuf(c) visible
    // counted vmcnt: V(c+1)/K(c+1) landed; K(c+2) stays IN FLIGHT
    if (c + 2 < NCH) {
      asm volatile("s_waitcnt vmcnt(1)" ::: "memory");
    } else {
      asm volatile("s_waitcnt vmcnt(0)" ::: "memory");
    }
    block_barrier();                                    // ONE barrier per chunk
  }

  // ---- Tail: PV(NCH-1) (vbuf/pbuf written before the last barrier) ----
  {
    const _Float16* vb = vbuf[(NCH - 1) % 3];
    const _Float16* pb = pbuf[(NCH - 1) & 1];
    #pragma unroll
    for (int t = 0; t < 2; ++t) {
      const int dcol = sub * 32 + t * 16 + lo16;
      #pragma unroll
      for (int ks = 0; ks < 2; ++ks) {
        const int pv_ = (ks * 4 + g) ^ (dcol & 7);
        f16x8 vf = *(const f16x8*)(vb + dcol * CH + pv_ * 8);
        f16x8 pf = *(const f16x8*)(pb + prow * CH + ((ks * 32 + g * 8) ^ ((prow & 7) << 3)));
        oacc[t] = __builtin_amdgcn_mfma_f32_16x16x32_f16(pf, vf, oacc[t], 0, 0, 0);
      }
    }
  }

  // ---- Epilogue: denominators, attn from regs, out from oacc ----
  ssum += __shfl_xor(ssum, 16);                 // reduce over g groups
  ssum += __shfl_xor(ssum, 32);
  if (lane < 16) redsum[qq][lane][sub] = ssum;
  __syncthreads();

  float denom = 0.f;
  #pragma unroll
  for (int j = 0; j < 4; ++j) denom += redsum[qq][lo16][j];
  const float inv = 1.0f / denom;

  // attn[q0+prow][c*64 + sub*16 + g*4 ..+3] = E' * inv (f32, from registers)
  float* arow = attn + ((size_t)bh * SS + q0 + prow) * SS + sub * 16 + g * 4;
  #pragma unroll
  for (int c = 0; c < NCH; ++c) {
    f32x4 pst = { (float)acc_h[c][0] * inv, (float)acc_h[c][1] * inv,
                  (float)acc_h[c][2] * inv, (float)acc_h[c][3] * inv };
    *(f32x4*)(arow + c * CH) = pst;
  }

  // out: C row = q = qq*16 + g*4 + i, col = d = sub*32 + t*16 + lo16
  float* O = out + hoff + (size_t)q0 * DD + sub * 32;
  #pragma unroll
  for (int i = 0; i < 4; ++i) {
    const int qr = g * 4 + i;
    float dq = 0.f;
    #pragma unroll
    for (int j = 0; j < 4; ++j) dq += redsum[qq][qr][j];
    const float rdq = 1.0f / dq;
    #pragma unroll
    for (int t = 0; t < 2; ++t)
      O[(size_t)(qq * 16 + qr) * DD + t * 16 + lo16] = oacc[t][i] * rdq;
  }
}

extern "C" void kernel_launch(void* const* d_in, const int* in_sizes, int n_in,
                              void* d_out, int out_size, void* d_ws, size_t ws_size,
                              hipStream_t stream) {
  const float* q    = (const float*)d_in[0];
  const float* k    = (const float*)d_in[1];
  const float* v    = (const float*)d_in[2];
  const int*   mask = (const int*)d_in[3];

  const size_t N = (size_t)BB * HH * SS * DD;     // 8388608
  float* out  = (float*)d_out;
  float* attn = out + N;                          // outputs concatenated (out, attn)

  // scratch: 3 f16 tensors = 48 MB
  _Float16* qh  = (_Float16*)d_ws;
  _Float16* kh  = qh + N;
  _Float16* vth = kh + N;

  cvt_f16  <<<N / 8 / 256, 256, 0, stream>>>(q, qh);
  knorm_f16<<<(BB * SS * DD) / 256, 256, 0, stream>>>(k, kh);
  vtrans_f16<<<dim3(DD / 32, SS / 32, BB * HH), dim3(32, 8), 0, stream>>>(v, vth);

  // 32 q-tiles x 32 heads, XCD-swizzled inside the kernel
  attn_fused<<<1024, 1024, 0, stream>>>(qh, kh, vth, mask, out, attn);
}